// Round 4
// baseline (217.019 us; speedup 1.0000x reference)
//
#include <hip/hip_runtime.h>
#include <math.h>

#define KDIM 256
#define NITER 50

// ws layout:
// int   cnt[512]      @ float offset 0     (memset to 0 every launch)
// float lossB[512]    @ float offset 512
// float psum[2048]    @ float offset 1024
// float ptrace[2048]  @ float offset 3072
// float pmin[2048]    @ float offset 5120

__global__ __launch_bounds__(256) void cacis_fused(
    const float* __restrict__ scores, const int* __restrict__ targets,
    const float* __restrict__ C,
    int* __restrict__ cnt, float* __restrict__ lossB,
    float* __restrict__ psum_o, float* __restrict__ ptrace_o, float* __restrict__ pmin_o)
{
    const int B0 = blockIdx.x;
    // XCD swizzle: blocks {b's 4 chunks} all land on XCD (b&7) under %8 round-robin
    const int b = ((B0 >> 5) << 3) | (B0 & 7);
    const int chunk = (B0 >> 3) & 3;
    const int tid = threadIdx.x, lane = tid & 63, wave = tid >> 6;
    const float* Cb = C + (size_t)b * KDIM * KDIM;
    const float4* C4 = (const float4*)Cb;

    __shared__ float4 sf4[KDIM/4];
    __shared__ float redS[256], redT[256], redM[256];
    __shared__ float rs[KDIM];
    __shared__ float aAll[KDIM];
    __shared__ float bcast[2];
    __shared__ int   iret;
    __shared__ int   wcnt[4];
    __shared__ int   sIdx[64];
    __shared__ float sLog[64];
    __shared__ float wm[4], wsm[4];

    const float* sf = (const float*)sf4;
    ((float*)sf4)[tid] = 0.5f * scores[b*KDIM + tid];
    __syncthreads();

    // ---------- phase 1: stream own chunk, partial sum/trace/min ----------
    const int row0 = chunk * 64;
    float psum = 0.f, ptrace = 0.f, pmin = INFINITY;
    #pragma unroll
    for (int rr = 0; rr < 16; ++rr) {
        const int row = row0 + wave + rr*4;
        float4 c4 = C4[row*(KDIM/4) + lane];
        float frow = sf[row];
        float4 fj = sf4[lane];
        psum += (c4.x + c4.y) + (c4.z + c4.w);
        pmin = fminf(pmin, fminf(fminf(frow+fj.x+c4.x, frow+fj.y+c4.y),
                                 fminf(frow+fj.z+c4.z, frow+fj.w+c4.w)));
        if ((row >> 2) == lane) {
            int r2 = row & 3;
            ptrace += (r2==0) ? c4.x : (r2==1) ? c4.y : (r2==2) ? c4.z : c4.w;
        }
    }
    redS[tid] = psum; redT[tid] = ptrace; redM[tid] = pmin;
    __syncthreads();
    for (int s = 128; s > 0; s >>= 1) {
        if (tid < s) {
            redS[tid] += redS[tid+s];
            redT[tid] += redT[tid+s];
            redM[tid]  = fminf(redM[tid], redM[tid+s]);
        }
        __syncthreads();
    }
    if (tid == 0) {
        const int slot = b*4 + chunk;
        __hip_atomic_store(&psum_o[slot],   redS[0], __ATOMIC_RELAXED, __HIP_MEMORY_SCOPE_AGENT);
        __hip_atomic_store(&ptrace_o[slot], redT[0], __ATOMIC_RELAXED, __HIP_MEMORY_SCOPE_AGENT);
        __hip_atomic_store(&pmin_o[slot],   redM[0], __ATOMIC_RELAXED, __HIP_MEMORY_SCOPE_AGENT);
        iret = __hip_atomic_fetch_add(&cnt[b], 1, __ATOMIC_ACQ_REL, __HIP_MEMORY_SCOPE_AGENT);
    }
    __syncthreads();
    if (iret != 3) return;   // not last for this batch -> done (no spinning, deadlock-free)

    // ---------- elected block: eps, minv from the 4 chunk partials ----------
    if (tid == 0) {
        float sum = 0.f, tr = 0.f, mn = INFINITY;
        #pragma unroll
        for (int k2 = 0; k2 < 4; ++k2) {
            sum += __hip_atomic_load(&psum_o[b*4+k2],   __ATOMIC_RELAXED, __HIP_MEMORY_SCOPE_AGENT);
            tr  += __hip_atomic_load(&ptrace_o[b*4+k2], __ATOMIC_RELAXED, __HIP_MEMORY_SCOPE_AGENT);
            mn   = fminf(mn, __hip_atomic_load(&pmin_o[b*4+k2], __ATOMIC_RELAXED, __HIP_MEMORY_SCOPE_AGENT));
        }
        bcast[0] = mn;
        bcast[1] = fmaxf((sum - tr) / (float)(KDIM*KDIM - KDIM), 1e-8f);
    }
    __syncthreads();
    const float minv = bcast[0];
    const float eps = bcast[1];
    const float inv_eps = 1.0f / eps;

    // ---------- rowsums of M over all 256 rows (L2-hot re-read) ----------
    #pragma unroll 4
    for (int rr = 0; rr < 64; ++rr) {
        const int row = rr*4 + wave;
        float4 c4 = C4[row*(KDIM/4) + lane];
        float frow = sf[row];
        float4 fj = sf4[lane];
        float p = __expf((minv - (frow+fj.x+c4.x)) * inv_eps)
                + __expf((minv - (frow+fj.y+c4.y)) * inv_eps)
                + __expf((minv - (frow+fj.z+c4.z)) * inv_eps)
                + __expf((minv - (frow+fj.w+c4.w)) * inv_eps);
        #pragma unroll
        for (int off = 32; off > 0; off >>= 1) p += __shfl_xor(p, off);
        if (lane == 0) rs[row] = p;
    }
    __syncthreads();

    // ---------- FW on wave 0: lane owns rows {lane, lane+64, lane+128, lane+192} ----------
    if (wave == 0) {
        const float f0 = sf[lane], f1 = sf[lane+64], f2 = sf[lane+128], f3 = sf[lane+192];
        const float* r0 = Cb + (size_t)lane*KDIM;
        const float* r1 = r0 + 64*KDIM;
        const float* r2 = r0 + 128*KDIM;
        const float* r3 = r0 + 192*KDIM;

        // global argmin of rowsum (grad0 direction), lowest-index tiebreak
        float v = rs[lane]; int vi = lane;
        float t;
        t = rs[lane+64];  if (t < v) { v = t; vi = lane+64; }
        t = rs[lane+128]; if (t < v) { v = t; vi = lane+128; }
        t = rs[lane+192]; if (t < v) { v = t; vi = lane+192; }
        #pragma unroll
        for (int off = 32; off > 0; off >>= 1) {
            float ov = __shfl_xor(v, off);
            int  ovi = __shfl_xor(vi, off);
            if (ov < v || (ov == v && ovi < vi)) { v = ov; vi = ovi; }
        }
        const int idx0 = vi;

        float fidx = sf[idx0];
        float g0 = 2.0f * __expf((minv - (f0 + fidx + r0[idx0])) * inv_eps);
        float g1 = 2.0f * __expf((minv - (f1 + fidx + r1[idx0])) * inv_eps);
        float g2 = 2.0f * __expf((minv - (f2 + fidx + r2[idx0])) * inv_eps);
        float g3 = 2.0f * __expf((minv - (f3 + fidx + r3[idx0])) * inv_eps);
        float a0 = (lane     == idx0) ? 1.0f : 0.0f;
        float a1 = (lane+64  == idx0) ? 1.0f : 0.0f;
        float a2 = (lane+128 == idx0) ? 1.0f : 0.0f;
        float a3 = (lane+192 == idx0) ? 1.0f : 0.0f;

        for (int it = 1; it < NITER; ++it) {
            float v2 = g0; int vi2 = lane;
            if (g1 < v2) { v2 = g1; vi2 = lane+64; }
            if (g2 < v2) { v2 = g2; vi2 = lane+128; }
            if (g3 < v2) { v2 = g3; vi2 = lane+192; }
            #pragma unroll
            for (int off = 32; off > 0; off >>= 1) {
                float ov = __shfl_xor(v2, off);
                int  ovi = __shfl_xor(vi2, off);
                if (ov < v2 || (ov == v2 && ovi < vi2)) { v2 = ov; vi2 = ovi; }
            }
            const int idx = vi2;
            const float gamma = 2.0f / ((float)it + 2.0f);
            const float omg = 1.0f - gamma;
            // fidx via in-register shfl (no LDS on the chain)
            const int which = idx >> 6;
            float fsel = (which==0) ? f0 : (which==1) ? f1 : (which==2) ? f2 : f3;
            const float fidx2 = __shfl(fsel, idx & 63);
            const float c0 = r0[idx], c1 = r1[idx], c2_ = r2[idx], c3 = r3[idx];
            g0 = omg*g0 + 2.0f*gamma*__expf((minv - (f0 + fidx2 + c0)) * inv_eps);
            g1 = omg*g1 + 2.0f*gamma*__expf((minv - (f1 + fidx2 + c1)) * inv_eps);
            g2 = omg*g2 + 2.0f*gamma*__expf((minv - (f2 + fidx2 + c2_)) * inv_eps);
            g3 = omg*g3 + 2.0f*gamma*__expf((minv - (f3 + fidx2 + c3)) * inv_eps);
            a0 = omg*a0 + ((lane     == idx) ? gamma : 0.0f);
            a1 = omg*a1 + ((lane+64  == idx) ? gamma : 0.0f);
            a2 = omg*a2 + ((lane+128 == idx) ? gamma : 0.0f);
            a3 = omg*a3 + ((lane+192 == idx) ? gamma : 0.0f);
        }
        aAll[lane]     = a0;
        aAll[lane+64]  = a1;
        aAll[lane+128] = a2;
        aAll[lane+192] = a3;
    }
    __syncthreads();

    const float a = aAll[tid];

    // ---------- support collection via ballot compaction ----------
    unsigned long long mask = __ballot(a > 0.f);
    if (lane == 0) wcnt[wave] = __popcll(mask);
    __syncthreads();
    int off0 = 0;
    for (int w = 0; w < wave; ++w) off0 += wcnt[w];
    const int count = wcnt[0] + wcnt[1] + wcnt[2] + wcnt[3];
    if (a > 0.f) {
        int pos = off0 + __popcll(mask & ((1ull << lane) - 1ull));
        sIdx[pos] = tid;
        sLog[pos] = logf(a);
    }
    __syncthreads();

    // ---------- logsumexp over support pairs ----------
    float m = -INFINITY, ss = 0.f;
    const int total = count * count;
    for (int p = tid; p < total; p += KDIM) {
        int ii = p / count;
        int jj = p - ii * count;
        int i = sIdx[ii], j = sIdx[jj];
        float cij = Cb[i*KDIM + j];
        float lm = (minv - (sf[i] + sf[j] + cij)) * inv_eps;
        float tt = sLog[ii] + sLog[jj] + lm;
        if (tt > m) { ss = ss * __expf(m - tt) + 1.0f; m = tt; }
        else        { ss += __expf(tt - m); }
    }
    #pragma unroll
    for (int off = 32; off > 0; off >>= 1) {
        float om = __shfl_xor(m, off);
        float os = __shfl_xor(ss, off);
        if (os > 0.f) {
            if (ss <= 0.f)   { m = om; ss = os; }
            else if (om > m) { ss = ss*__expf(m-om) + os; m = om; }
            else             { ss += os*__expf(om-m); }
        }
    }
    if (lane == 0) { wm[wave] = m; wsm[wave] = ss; }
    __syncthreads();
    if (tid == 0) {
        float M = wm[0], S = wsm[0];
        #pragma unroll
        for (int w = 1; w < 4; ++w) {
            float om = wm[w], os = wsm[w];
            if (os > 0.f) {
                if (S <= 0.f)    { M = om; S = os; }
                else if (om > M) { S = S*__expf(M-om) + os; M = om; }
                else             { S += os*__expf(om-M); }
            }
        }
        float logval = M + logf(S);
        float shift = -minv * inv_eps;
        float conjugate = -eps * (logval + shift);
        float fy = scores[b*KDIM + targets[b]];
        lossB[b] = conjugate - fy;
    }
}

__global__ __launch_bounds__(512) void cacis_reduce(const float* __restrict__ lossB,
                                                    float* __restrict__ out, int B)
{
    __shared__ float red[512];
    int t = threadIdx.x;
    red[t] = (t < B) ? lossB[t] : 0.f;
    __syncthreads();
    for (int s = 256; s > 0; s >>= 1) { if (t < s) red[t] += red[t+s]; __syncthreads(); }
    if (t == 0) out[0] = red[0] / (float)B;
}

extern "C" void kernel_launch(void* const* d_in, const int* in_sizes, int n_in,
                              void* d_out, int out_size, void* d_ws, size_t ws_size,
                              hipStream_t stream) {
    const float* scores  = (const float*)d_in[0];
    const int*   targets = (const int*)d_in[1];
    const float* C       = (const float*)d_in[2];
    float* out = (float*)d_out;
    const int B = in_sizes[1];   // 512

    float* ws     = (float*)d_ws;
    int*   cnt    = (int*)ws;
    float* lossB  = ws + 512;
    float* psum   = ws + 1024;
    float* ptrace = ws + 3072;
    float* pmin   = ws + 5120;

    hipMemsetAsync(cnt, 0, B * sizeof(int), stream);   // election counters must start at 0
    cacis_fused<<<B*4, 256, 0, stream>>>(scores, targets, C, cnt, lossB, psum, ptrace, pmin);
    cacis_reduce<<<1, 512, 0, stream>>>(lossB, out, B);
}

// Round 5
// 107.883 us; speedup vs baseline: 2.0116x; 2.0116x over previous
//
#include <hip/hip_runtime.h>
#include <math.h>

#define KDIM 256
#define NITER 50

// ws layout (floats):
// [0,2048)      psum per (b,chunk)
// [2048,4096)   ptrace
// [4096,6144)   pmin
// [6144,6656)   lossB

__global__ __launch_bounds__(256) void k1_partials(
    const float* __restrict__ scores, const float* __restrict__ C,
    float* __restrict__ psum_o, float* __restrict__ ptrace_o, float* __restrict__ pmin_o)
{
    const int blk = blockIdx.x;
    const int b = blk >> 2, chunk = blk & 3;
    const int tid = threadIdx.x, lane = tid & 63, wave = tid >> 6;
    const float4* C4 = (const float4*)(C + (size_t)b * KDIM * KDIM);

    __shared__ float4 sf4[KDIM/4];
    __shared__ float redS[256], redT[256], redM[256];
    const float* sf = (const float*)sf4;
    ((float*)sf4)[tid] = 0.5f * scores[b*KDIM + tid];
    __syncthreads();

    const int row0 = chunk * 64;
    float psum = 0.f, ptrace = 0.f, pmin = INFINITY;
    #pragma unroll
    for (int rr = 0; rr < 16; ++rr) {
        const int row = row0 + wave + rr*4;
        float4 c4 = C4[row*(KDIM/4) + lane];
        float frow = sf[row];
        float4 fj = sf4[lane];
        psum += (c4.x + c4.y) + (c4.z + c4.w);
        pmin = fminf(pmin, fminf(fminf(frow+fj.x+c4.x, frow+fj.y+c4.y),
                                 fminf(frow+fj.z+c4.z, frow+fj.w+c4.w)));
        if ((row >> 2) == lane) {
            int r2 = row & 3;
            ptrace += (r2==0) ? c4.x : (r2==1) ? c4.y : (r2==2) ? c4.z : c4.w;
        }
    }
    redS[tid] = psum; redT[tid] = ptrace; redM[tid] = pmin;
    __syncthreads();
    for (int s = 128; s > 0; s >>= 1) {
        if (tid < s) {
            redS[tid] += redS[tid+s];
            redT[tid] += redT[tid+s];
            redM[tid]  = fminf(redM[tid], redM[tid+s]);
        }
        __syncthreads();
    }
    if (tid == 0) { psum_o[blk] = redS[0]; ptrace_o[blk] = redT[0]; pmin_o[blk] = redM[0]; }
}

__global__ __launch_bounds__(512) void k23_fw(
    const float* __restrict__ scores, const int* __restrict__ targets,
    const float* __restrict__ C,
    const float* __restrict__ psum_i, const float* __restrict__ ptrace_i, const float* __restrict__ pmin_i,
    float* __restrict__ lossB)
{
    const int b = blockIdx.x;
    const int tid = threadIdx.x, lane = tid & 63, wave = tid >> 6;  // 8 waves
    const float* Cb = C + (size_t)b * KDIM * KDIM;
    const float4* C4 = (const float4*)Cb;

    __shared__ float4 sf4[KDIM/4];
    __shared__ float rs[KDIM];
    __shared__ float aAll[KDIM];
    __shared__ int   wcnt[8];
    __shared__ int   sIdx[64];
    __shared__ float sLog[64];
    __shared__ float wm[8], wsm[8];

    const float* sf = (const float*)sf4;
    if (tid < KDIM) ((float*)sf4)[tid] = 0.5f * scores[b*KDIM + tid];
    __syncthreads();

    // eps, minv from k1 partials (all threads, redundant scalar loads)
    float sum = 0.f, tr = 0.f, mn = INFINITY;
    #pragma unroll
    for (int c2 = 0; c2 < 4; ++c2) {
        sum += psum_i[b*4 + c2];
        tr  += ptrace_i[b*4 + c2];
        mn   = fminf(mn, pmin_i[b*4 + c2]);
    }
    const float eps = fmaxf((sum - tr) / (float)(KDIM*KDIM - KDIM), 1e-8f);
    const float inv_eps = 1.0f / eps;
    const float minv = mn;

    // ---------- rowsums of M over all 256 rows (L3-resident read), 8 waves ----------
    #pragma unroll 8
    for (int rr = 0; rr < 32; ++rr) {
        const int row = rr*8 + wave;
        float4 c4 = C4[row*(KDIM/4) + lane];
        float frow = sf[row];
        float4 fj = sf4[lane];
        float p = __expf((minv - (frow+fj.x+c4.x)) * inv_eps)
                + __expf((minv - (frow+fj.y+c4.y)) * inv_eps)
                + __expf((minv - (frow+fj.z+c4.z)) * inv_eps)
                + __expf((minv - (frow+fj.w+c4.w)) * inv_eps);
        #pragma unroll
        for (int off = 32; off > 0; off >>= 1) p += __shfl_xor(p, off);
        if (lane == 0) rs[row] = p;
    }
    __syncthreads();

    // ---------- FW on wave 0: lane owns rows {lane, lane+64, lane+128, lane+192} ----------
    if (wave == 0) {
        const float f0 = sf[lane], f1 = sf[lane+64], f2 = sf[lane+128], f3 = sf[lane+192];
        const float* r0 = Cb + (size_t)lane*KDIM;
        const float* r1 = r0 + 64*KDIM;
        const float* r2 = r0 + 128*KDIM;
        const float* r3 = r0 + 192*KDIM;

        // argmin of rowsum (grad0 direction), lowest-index tiebreak
        float v = rs[lane]; int vi = lane;
        float t;
        t = rs[lane+64];  if (t < v) { v = t; vi = lane+64; }
        t = rs[lane+128]; if (t < v) { v = t; vi = lane+128; }
        t = rs[lane+192]; if (t < v) { v = t; vi = lane+192; }
        #pragma unroll
        for (int off = 32; off > 0; off >>= 1) {
            float ov = __shfl_xor(v, off);
            int  ovi = __shfl_xor(vi, off);
            if (ov < v || (ov == v && ovi < vi)) { v = ov; vi = ovi; }
        }
        const int idx0 = vi;

        float fidx = sf[idx0];
        float g0 = 2.0f * __expf((minv - (f0 + fidx + r0[idx0])) * inv_eps);
        float g1 = 2.0f * __expf((minv - (f1 + fidx + r1[idx0])) * inv_eps);
        float g2 = 2.0f * __expf((minv - (f2 + fidx + r2[idx0])) * inv_eps);
        float g3 = 2.0f * __expf((minv - (f3 + fidx + r3[idx0])) * inv_eps);
        float a0 = (lane     == idx0) ? 1.0f : 0.0f;
        float a1 = (lane+64  == idx0) ? 1.0f : 0.0f;
        float a2 = (lane+128 == idx0) ? 1.0f : 0.0f;
        float a3 = (lane+192 == idx0) ? 1.0f : 0.0f;

        for (int it = 1; it < NITER; ++it) {
            float v2 = g0; int vi2 = lane;
            if (g1 < v2) { v2 = g1; vi2 = lane+64; }
            if (g2 < v2) { v2 = g2; vi2 = lane+128; }
            if (g3 < v2) { v2 = g3; vi2 = lane+192; }
            #pragma unroll
            for (int off = 32; off > 0; off >>= 1) {
                float ov = __shfl_xor(v2, off);
                int  ovi = __shfl_xor(vi2, off);
                if (ov < v2 || (ov == v2 && ovi < vi2)) { v2 = ov; vi2 = ovi; }
            }
            const int idx = vi2;
            const float gamma = 2.0f / ((float)it + 2.0f);
            const float omg = 1.0f - gamma;
            const int which = idx >> 6;
            float fsel = (which==0) ? f0 : (which==1) ? f1 : (which==2) ? f2 : f3;
            const float fidx2 = __shfl(fsel, idx & 63);
            const float c0 = r0[idx], c1 = r1[idx], c2_ = r2[idx], c3 = r3[idx];
            g0 = omg*g0 + 2.0f*gamma*__expf((minv - (f0 + fidx2 + c0)) * inv_eps);
            g1 = omg*g1 + 2.0f*gamma*__expf((minv - (f1 + fidx2 + c1)) * inv_eps);
            g2 = omg*g2 + 2.0f*gamma*__expf((minv - (f2 + fidx2 + c2_)) * inv_eps);
            g3 = omg*g3 + 2.0f*gamma*__expf((minv - (f3 + fidx2 + c3)) * inv_eps);
            a0 = omg*a0 + ((lane     == idx) ? gamma : 0.0f);
            a1 = omg*a1 + ((lane+64  == idx) ? gamma : 0.0f);
            a2 = omg*a2 + ((lane+128 == idx) ? gamma : 0.0f);
            a3 = omg*a3 + ((lane+192 == idx) ? gamma : 0.0f);
        }
        aAll[lane]     = a0;
        aAll[lane+64]  = a1;
        aAll[lane+128] = a2;
        aAll[lane+192] = a3;
    }
    __syncthreads();

    const float a = (tid < KDIM) ? aAll[tid] : 0.f;

    // ---------- support collection via ballot compaction (<=50, tid-ordered) ----------
    unsigned long long mask = __ballot(a > 0.f);
    if (lane == 0) wcnt[wave] = __popcll(mask);   // waves 4..7 contribute 0
    __syncthreads();
    int off0 = 0;
    for (int w = 0; w < wave; ++w) off0 += wcnt[w];
    int count = 0;
    #pragma unroll
    for (int w = 0; w < 8; ++w) count += wcnt[w];
    if (a > 0.f) {
        int pos = off0 + __popcll(mask & ((1ull << lane) - 1ull));
        sIdx[pos] = tid;
        sLog[pos] = logf(a);
    }
    __syncthreads();

    // ---------- logsumexp over support pairs (online max+sum), 512 threads ----------
    float m = -INFINITY, ss = 0.f;
    const int total = count * count;
    for (int p = tid; p < total; p += 512) {
        int ii = p / count;
        int jj = p - ii * count;
        int i = sIdx[ii], j = sIdx[jj];
        float cij = Cb[i*KDIM + j];
        float lm = (minv - (sf[i] + sf[j] + cij)) * inv_eps;
        float tt = sLog[ii] + sLog[jj] + lm;
        if (tt > m) { ss = ss * __expf(m - tt) + 1.0f; m = tt; }
        else        { ss += __expf(tt - m); }
    }
    #pragma unroll
    for (int off = 32; off > 0; off >>= 1) {
        float om = __shfl_xor(m, off);
        float os = __shfl_xor(ss, off);
        if (os > 0.f) {
            if (ss <= 0.f)   { m = om; ss = os; }
            else if (om > m) { ss = ss*__expf(m-om) + os; m = om; }
            else             { ss += os*__expf(om-m); }
        }
    }
    if (lane == 0) { wm[wave] = m; wsm[wave] = ss; }
    __syncthreads();
    if (tid == 0) {
        float M = wm[0], S = wsm[0];
        #pragma unroll
        for (int w = 1; w < 8; ++w) {
            float om = wm[w], os = wsm[w];
            if (os > 0.f) {
                if (S <= 0.f)    { M = om; S = os; }
                else if (om > M) { S = S*__expf(M-om) + os; M = om; }
                else             { S += os*__expf(om-M); }
            }
        }
        float logval = M + logf(S);
        float shift = -minv * inv_eps;
        float conjugate = -eps * (logval + shift);
        float fy = scores[b*KDIM + targets[b]];
        lossB[b] = conjugate - fy;
    }
}

__global__ __launch_bounds__(512) void cacis_reduce(const float* __restrict__ lossB,
                                                    float* __restrict__ out, int B)
{
    __shared__ float red[512];
    int t = threadIdx.x;
    red[t] = (t < B) ? lossB[t] : 0.f;
    __syncthreads();
    for (int s = 256; s > 0; s >>= 1) { if (t < s) red[t] += red[t+s]; __syncthreads(); }
    if (t == 0) out[0] = red[0] / (float)B;
}

extern "C" void kernel_launch(void* const* d_in, const int* in_sizes, int n_in,
                              void* d_out, int out_size, void* d_ws, size_t ws_size,
                              hipStream_t stream) {
    const float* scores  = (const float*)d_in[0];
    const int*   targets = (const int*)d_in[1];
    const float* C       = (const float*)d_in[2];
    float* out = (float*)d_out;
    const int B = in_sizes[1];   // 512

    float* ws     = (float*)d_ws;
    float* psum   = ws;
    float* ptrace = ws + 2048;
    float* pmin   = ws + 4096;
    float* lossB  = ws + 6144;

    k1_partials<<<B*4, 256, 0, stream>>>(scores, C, psum, ptrace, pmin);
    k23_fw     <<<B,   512, 0, stream>>>(scores, targets, C, psum, ptrace, pmin, lossB);
    cacis_reduce<<<1, 512, 0, stream>>>(lossB, out, B);
}